// Round 4
// baseline (237.006 us; speedup 1.0000x reference)
//
#include <hip/hip_runtime.h>
#include <float.h>
#include <math.h>

#define NPTS 16384
#define HDIM 256

__device__ __forceinline__ float silu_f(float z) {
    return z / (1.0f + __expf(-z));
}

// ---------------------------------------------------------------------------
// Kernel 1: mean of 6-NN distances per row.
// Wave-shared top-7 per row, R=4 rows per wave (amortizes LDS reads 4x),
// 4 points per lane per iter via two lane-contiguous ds_read_b128 (no bank
// conflicts). Selection key e = |p|^2 - 2 q.p  (|q|^2 added back at the end;
// same expansion as the reference). Inserts: rare scalar-branched ballot loop.
// NOTE: xy4 is float4 = TWO points; full range is NPTS/2 float4 (r3 bug was
// NPTS/4 -> scanned only half the points).
// ---------------------------------------------------------------------------
__global__ __launch_bounds__(256) void knn_kernel(const float* __restrict__ xyf,
                                                  float* __restrict__ md) {
    __shared__ float4 tile4[1024];              // 2048 points, 16 KB
    const float4* xy4 = (const float4*)xyf;
    const float2* xy2 = (const float2*)xyf;
    const int lane  = threadIdx.x & 63;
    const int wv    = threadIdx.x >> 6;
    const int rbase = blockIdx.x * 16 + wv * 4; // 4 rows per wave, 16 per block

    float m2x[4], m2y[4], r2q[4];
    #pragma unroll
    for (int q = 0; q < 4; ++q) {
        const float2 Q = xy2[rbase + q];
        m2x[q] = -2.0f * Q.x;
        m2y[q] = -2.0f * Q.y;
        r2q[q] = fmaf(Q.x, Q.x, Q.y * Q.y);
    }

    float s[4][7];
    #pragma unroll
    for (int q = 0; q < 4; ++q)
        #pragma unroll
        for (int i = 0; i < 7; ++i) s[q][i] = FLT_MAX;

    for (int t0 = 0; t0 < NPTS / 2; t0 += 1024) {   // 8 tiles x 2048 points
        __syncthreads();
        for (int i = threadIdx.x; i < 1024; i += 256) tile4[i] = xy4[t0 + i];
        __syncthreads();

        for (int jj = 0; jj < 1024; jj += 128) {
            const float4 A = tile4[jj + lane];        // stride-1: conflict-free
            const float4 B = tile4[jj + 64 + lane];
            const float r0 = fmaf(A.x, A.x, A.y * A.y);
            const float r1 = fmaf(A.z, A.z, A.w * A.w);
            const float r2 = fmaf(B.x, B.x, B.y * B.y);
            const float r3 = fmaf(B.z, B.z, B.w * B.w);

            #pragma unroll
            for (int q = 0; q < 4; ++q) {
                float e0 = fmaf(m2x[q], A.x, fmaf(m2y[q], A.y, r0));
                float e1 = fmaf(m2x[q], A.z, fmaf(m2y[q], A.w, r1));
                float e2 = fmaf(m2x[q], B.x, fmaf(m2y[q], B.y, r2));
                float e3 = fmaf(m2x[q], B.z, fmaf(m2y[q], B.w, r3));
                float mv = fminf(fminf(e0, e1), fminf(e2, e3));

                unsigned long long m = __ballot(mv < s[q][6]);
                while (m) {                           // rare after warmup
                    const int L = __ffsll(m) - 1;
                    const float v = __int_as_float(
                        __builtin_amdgcn_readlane(__float_as_int(mv), L));
                    s[q][6] = fmaxf(s[q][5], v);
                    s[q][5] = fmaxf(s[q][4], fminf(s[q][5], v));
                    s[q][4] = fmaxf(s[q][3], fminf(s[q][4], v));
                    s[q][3] = fmaxf(s[q][2], fminf(s[q][3], v));
                    s[q][2] = fmaxf(s[q][1], fminf(s[q][2], v));
                    s[q][1] = fmaxf(s[q][0], fminf(s[q][1], v));
                    s[q][0] = fminf(s[q][0], v);
                    if (lane == L) {                  // consume the candidate
                        if      (e0 == mv) e0 = FLT_MAX;
                        else if (e1 == mv) e1 = FLT_MAX;
                        else if (e2 == mv) e2 = FLT_MAX;
                        else               e3 = FLT_MAX;
                        mv = fminf(fminf(e0, e1), fminf(e2, e3));
                    }
                    m = __ballot(mv < s[q][6]);
                }
            }
        }
    }

    if (lane == 0) {
        #pragma unroll
        for (int q = 0; q < 4; ++q) {
            float sum = 0.0f;
            #pragma unroll
            for (int i = 1; i < 7; ++i)
                sum += sqrtf(fmaxf(s[q][i] + r2q[q], 1e-12f));
            md[rbase + q] = sum * (1.0f / 6.0f);
        }
    }
}

// ---------------------------------------------------------------------------
// Kernel 2: fused  out = silu(x@W1+b1)@W2 + b2 + silu(md@Wd1+bd1)@Wd2 + bd2
// 16 points x 256 cols per block, 1024 blocks (4 waves/SIMD of total work).
// Thread = 4 cols x 4 points, 16 accumulators. h1 staged [k][p] stride 20
// (16B-aligned rows); main-loop h1 reads are wave-uniform broadcast b128.
// W2/Wd2 row loads depth-2 software-pipelined.
// ---------------------------------------------------------------------------
__global__ __launch_bounds__(256) void mlp_kernel(
        const float* __restrict__ xyf,
        const float* __restrict__ W1,  const float* __restrict__ b1,
        const float* __restrict__ W2,  const float* __restrict__ b2,
        const float* __restrict__ Wd1, const float* __restrict__ bd1,
        const float* __restrict__ Wd2, const float* __restrict__ bd2,
        const float* __restrict__ md,  float* __restrict__ out) {
    __shared__ __align__(16) float hT[256 * 20];   // 20 KB
    __shared__ float2 sxy[16];
    __shared__ float  smd[16];

    const int tid   = threadIdx.x;
    const int pbase = blockIdx.x * 16;

    if (tid < 16) {
        sxy[tid] = ((const float2*)xyf)[pbase + tid];
        smd[tid] = md[pbase + tid];
    }
    __syncthreads();

    // phase A: h1[k][p] = silu(x[p]@W1[:,k] + b1[k]), k = tid
    {
        const int k = tid;
        const float w0 = W1[k], w1 = W1[HDIM + k], b = b1[k];
        #pragma unroll
        for (int p = 0; p < 16; ++p) {
            const float2 xp = sxy[p];
            hT[k * 20 + p] = silu_f(fmaf(xp.x, w0, fmaf(xp.y, w1, b)));
        }
    }
    __syncthreads();

    const int tx = tid & 63;
    const int ty = tid >> 6;
    const int c0 = tx * 4;
    const int p0 = ty * 4;

    float acc[4][4];
    #pragma unroll
    for (int p = 0; p < 4; ++p)
        #pragma unroll
        for (int c = 0; c < 4; ++c) acc[p][c] = 0.0f;

    // main GEMM: acc += h1 @ W2, depth-2 pipelined W row loads
    {
        const float* W2c = W2 + c0;
        float4 wa = *(const float4*)(W2c);
        float4 wb = *(const float4*)(W2c + HDIM);
        for (int k = 0; k < 256; k += 2) {
            const int kn = (k + 2 < 256) ? (k + 2) : 254;
            const float4 wc = *(const float4*)(W2c + kn * HDIM);
            const float4 wd = *(const float4*)(W2c + kn * HDIM + HDIM);
            const float4 a0 = *(const float4*)(&hT[k * 20 + p0]);       // broadcast
            const float4 a1 = *(const float4*)(&hT[(k + 1) * 20 + p0]); // broadcast
            const float ak[4] = {a0.x, a0.y, a0.z, a0.w};
            const float al[4] = {a1.x, a1.y, a1.z, a1.w};
            #pragma unroll
            for (int p = 0; p < 4; ++p) {
                acc[p][0] = fmaf(ak[p], wa.x, acc[p][0]);
                acc[p][1] = fmaf(ak[p], wa.y, acc[p][1]);
                acc[p][2] = fmaf(ak[p], wa.z, acc[p][2]);
                acc[p][3] = fmaf(ak[p], wa.w, acc[p][3]);
            }
            #pragma unroll
            for (int p = 0; p < 4; ++p) {
                acc[p][0] = fmaf(al[p], wb.x, acc[p][0]);
                acc[p][1] = fmaf(al[p], wb.y, acc[p][1]);
                acc[p][2] = fmaf(al[p], wb.z, acc[p][2]);
                acc[p][3] = fmaf(al[p], wb.w, acc[p][3]);
            }
            wa = wc; wb = wd;
        }
    }
    __syncthreads();

    // phase B: g[j][p] = silu(md[p]*Wd1[j] + bd1[j]), j = tid < 128
    if (tid < 128) {
        const int j = tid;
        const float wd = Wd1[j], bd = bd1[j];
        #pragma unroll
        for (int p = 0; p < 16; ++p)
            hT[j * 20 + p] = silu_f(fmaf(smd[p], wd, bd));
    }
    __syncthreads();

    // acc += g @ Wd2, depth-2 pipelined
    {
        const float* Wdc = Wd2 + c0;
        float4 wa = *(const float4*)(Wdc);
        float4 wb = *(const float4*)(Wdc + HDIM);
        for (int k = 0; k < 128; k += 2) {
            const int kn = (k + 2 < 128) ? (k + 2) : 126;
            const float4 wc = *(const float4*)(Wdc + kn * HDIM);
            const float4 wd = *(const float4*)(Wdc + kn * HDIM + HDIM);
            const float4 a0 = *(const float4*)(&hT[k * 20 + p0]);
            const float4 a1 = *(const float4*)(&hT[(k + 1) * 20 + p0]);
            const float ak[4] = {a0.x, a0.y, a0.z, a0.w};
            const float al[4] = {a1.x, a1.y, a1.z, a1.w};
            #pragma unroll
            for (int p = 0; p < 4; ++p) {
                acc[p][0] = fmaf(ak[p], wa.x, acc[p][0]);
                acc[p][1] = fmaf(ak[p], wa.y, acc[p][1]);
                acc[p][2] = fmaf(ak[p], wa.z, acc[p][2]);
                acc[p][3] = fmaf(ak[p], wa.w, acc[p][3]);
            }
            #pragma unroll
            for (int p = 0; p < 4; ++p) {
                acc[p][0] = fmaf(al[p], wb.x, acc[p][0]);
                acc[p][1] = fmaf(al[p], wb.y, acc[p][1]);
                acc[p][2] = fmaf(al[p], wb.z, acc[p][2]);
                acc[p][3] = fmaf(al[p], wb.w, acc[p][3]);
            }
            wa = wc; wb = wd;
        }
    }

    // epilogue: + b2 + bd2, coalesced float4 stores
    const float4 v2 = *(const float4*)(b2 + c0);
    const float4 vd = *(const float4*)(bd2 + c0);
    #pragma unroll
    for (int p = 0; p < 4; ++p) {
        float4 o;
        o.x = acc[p][0] + v2.x + vd.x;
        o.y = acc[p][1] + v2.y + vd.y;
        o.z = acc[p][2] + v2.z + vd.z;
        o.w = acc[p][3] + v2.w + vd.w;
        *(float4*)(out + (size_t)(pbase + p0 + p) * HDIM + c0) = o;
    }
}

extern "C" void kernel_launch(void* const* d_in, const int* in_sizes, int n_in,
                              void* d_out, int out_size, void* d_ws, size_t ws_size,
                              hipStream_t stream) {
    const float* xy  = (const float*)d_in[0];
    const float* W1  = (const float*)d_in[1];
    const float* b1  = (const float*)d_in[2];
    const float* W2  = (const float*)d_in[3];
    const float* b2  = (const float*)d_in[4];
    const float* Wd1 = (const float*)d_in[5];
    const float* bd1 = (const float*)d_in[6];
    const float* Wd2 = (const float*)d_in[7];
    const float* bd2 = (const float*)d_in[8];
    // d_in[9] is k == 6 (fixed by setup_inputs; kernels hard-code top-7)
    float* out = (float*)d_out;
    float* md  = (float*)d_ws;  // 16384 floats of scratch for mean distances

    knn_kernel<<<NPTS / 16, 256, 0, stream>>>(xy, md);
    mlp_kernel<<<NPTS / 16, 256, 0, stream>>>(xy, W1, b1, W2, b2,
                                              Wd1, bd1, Wd2, bd2, md, out);
}